// Round 10
// baseline (415.197 us; speedup 1.0000x reference)
//
#include <hip/hip_runtime.h>
#include <hip/hip_bf16.h>
#include <hip/hip_cooperative_groups.h>

namespace cg = cooperative_groups;

#define N_NODES 100000
#define N_EDGES 1000000
#define NBLK 256
#define NTHR 1024
#define SPAN 391              // ceil(N_NODES / NBLK)

// superrange partitioning (hist/coff granularity)
#define RANGES 4
#define RSIZE  25000
#define RWORDS 12500          // u32 words (2 x u16 per word)
#define CHUNKS 32
#define CHUNK_EDGES (N_EDGES / CHUNKS)   // 31250
// fill granularity: 8 half-ranges
#define HRSIZE  12500
#define HRWORDS 6250

// ---------------- workspace layout (bytes) ----------------
// ghist_s   [0         .. 6,400,000)   u32[128*12500]
// ghist_r   [6,400,000 ..12,800,000)   u32[128*12500]
// coff      [12,800,000..25,600,000)   int[128*25000]
// pre_r     [25,600,000..26,000,000)   int[N]   in-block exclusive prefix
// row_start [26,000,000..26,400,016)   int[N+1]
// gsum      [26,400,016..26,401,040)   int[256]
// goff      [26,401,040..26,402,064)   int[256]
// rs        [26,403,200..26,803,200)   float[N]
// col       [26,803,200..30,803,200)   int[E]
// h16       [30,803,200..43,603,200)   ushort[N*64] bf16
// z         [43,603,200..44,003,200)   float[N]
// NO memset: every buffer densely overwritten before first read.

__device__ __forceinline__ unsigned f32_to_bf16(float v) {
    unsigned u = __float_as_uint(v);
    return (u + 0x7fffu + ((u >> 16) & 1u)) >> 16;     // RNE
}
__device__ __forceinline__ float bf16_to_f32(unsigned b) {
    return __uint_as_float(b << 16);
}

extern "C" __global__ void __launch_bounds__(NTHR)
k_mega(const int* __restrict__ senders, const int* __restrict__ receivers,
       const float* __restrict__ emb, const float* __restrict__ W1,
       const float* __restrict__ W2, const float* __restrict__ b2,
       unsigned* __restrict__ ghist_s, unsigned* __restrict__ ghist_r,
       int* __restrict__ coff, int* __restrict__ pre_r,
       int* __restrict__ row_start, int* __restrict__ gsum,
       int* __restrict__ goff, float* __restrict__ rs,
       int* __restrict__ col, unsigned short* __restrict__ h16,
       float* __restrict__ z, float* __restrict__ out) {
    cg::grid_group grid = cg::this_grid();
    __shared__ unsigned lds[RWORDS];   // 50 KB, reused per phase
    const int b = blockIdx.x;
    const int t = threadIdx.x;

    // ================= P0: histograms (block = arr x superrange x chunk) ====
    {
        int arr = b >> 7, rem = b & 127, r = rem >> 5, c = rem & 31;
        const int* __restrict__ src = arr ? receivers : senders;
        unsigned* __restrict__ gh   = arr ? ghist_r : ghist_s;
        for (int w = t; w < RWORDS; w += NTHR) lds[w] = 0u;
        __syncthreads();
        int base = r * RSIZE, beg = c * CHUNK_EDGES, end = beg + CHUNK_EDGES;
        for (int i = beg + t; i < end; i += NTHR) {
            unsigned idx = (unsigned)(src[i] - base);
            if (idx < (unsigned)RSIZE)
                atomicAdd(&lds[idx >> 1], 1u << ((idx & 1) * 16));
        }
        __syncthreads();
        unsigned* __restrict__ dst = gh + (size_t)rem * RWORDS;
        for (int w = t; w < RWORDS; w += NTHR) dst[w] = lds[w];
    }
    grid.sync();

    // ===== P1: per-node recv count + rs; in-block exclusive prefix; gsum ====
    {
        int* s = (int*)lds;
        int idx = b * SPAN + t;
        int v = 0;
        if (t < SPAN && idx < N_NODES) {
            int r = idx / RSIZE;
            int bin = idx - r * RSIZE;
            int w = bin >> 1, sh = (bin & 1) * 16;
            const unsigned* __restrict__ gr = ghist_r + (size_t)(r * CHUNKS) * RWORDS + w;
            const unsigned* __restrict__ gs = ghist_s + (size_t)(r * CHUNKS) * RWORDS + w;
            unsigned sr_ = 0, ss_ = 0;
#pragma unroll
            for (int c = 0; c < CHUNKS; ++c) {
                sr_ += (gr[(size_t)c * RWORDS] >> sh) & 0xffffu;
                ss_ += (gs[(size_t)c * RWORDS] >> sh) & 0xffffu;
            }
            v = (int)sr_;
            rs[idx] = rsqrtf(fmaxf((float)ss_, 1.0f));
        }
        if (t < 512) s[t] = v;
        __syncthreads();
        for (int off = 1; off < 512; off <<= 1) {
            int x = (t < 512 && t >= off) ? s[t - off] : 0;
            __syncthreads();
            if (t < 512) s[t] += x;
            __syncthreads();
        }
        if (t < SPAN && idx < N_NODES) pre_r[idx] = s[t] - v;
        if (t == 511) gsum[b] = s[511];
    }
    grid.sync();

    // ================= P2: block 0 scans gsum -> goff (exclusive) ===========
    if (b == 0) {
        int* s = (int*)lds;
        int v = (t < NBLK) ? gsum[t] : 0;
        if (t < NBLK) s[t] = v;
        __syncthreads();
        for (int off = 1; off < NBLK; off <<= 1) {
            int x = (t < NBLK && t >= off) ? s[t - off] : 0;
            __syncthreads();
            if (t < NBLK) s[t] += x;
            __syncthreads();
        }
        if (t < NBLK) goff[t] = s[t] - v;
    }
    grid.sync();

    // ================= P3: row_start + per-chunk coff =======================
    {
        int idx = b * SPAN + t;
        if (t < SPAN && idx < N_NODES) {
            int run = goff[b] + pre_r[idx];
            row_start[idx] = run;
            int r = idx / RSIZE;
            int bin = idx - r * RSIZE;
            int w = bin >> 1, sh = (bin & 1) * 16;
            const unsigned* __restrict__ gr = ghist_r + (size_t)(r * CHUNKS) * RWORDS + w;
            int* __restrict__ co = coff + (size_t)(r * CHUNKS) * RSIZE + bin;
#pragma unroll
            for (int c = 0; c < CHUNKS; ++c) {
                co[(size_t)c * RSIZE] = run;
                run += (int)((gr[(size_t)c * RWORDS] >> sh) & 0xffffu);
            }
        }
        if (b == 0 && t == 0) row_start[N_NODES] = N_EDGES;
    }
    grid.sync();

    // ====== P4: atomic-free CSR fill (half-range x chunk) + h16 compute =====
    {
        int r8 = b >> 5;           // half-range 0..7
        int c  = b & 31;           // chunk 0..31
        int sr = r8 >> 1, hs = r8 & 1;
        for (int w = t; w < HRWORDS; w += NTHR) lds[w] = 0u;
        __syncthreads();
        int base = r8 * HRSIZE;
        int beg  = c * CHUNK_EDGES, end = beg + CHUNK_EDGES;
        const int* __restrict__ co =
            coff + (size_t)(sr * CHUNKS + c) * RSIZE + hs * HRSIZE;
        for (int i = beg + t; i < end; i += NTHR) {
            unsigned idx = (unsigned)(receivers[i] - base);
            if (idx < (unsigned)HRSIZE) {
                int sh = (idx & 1) * 16;
                unsigned old = atomicAdd(&lds[idx >> 1], 1u << sh);
                int rank = (int)((old >> sh) & 0xffffu);
                col[co[idx] + rank] = senders[i];
            }
        }
        // --- h16[n] = bf16((emb[n]*rs[n]) @ W1), independent of fill above
        int lane = t & 63;
        int wib  = t >> 6;
        int gw   = b * 16 + wib;           // 4096 waves
        const int nw = NBLK * 16;
        float w1c[64];
#pragma unroll
        for (int k = 0; k < 64; ++k) w1c[k] = W1[k * 64 + lane];
        for (int n = gw; n < N_NODES; n += nw) {
            float e = emb[(size_t)n * 64 + lane] * rs[n];
            float a = 0.f;
            int ei = __float_as_int(e);
#pragma unroll
            for (int k = 0; k < 64; ++k)
                a += __int_as_float(__builtin_amdgcn_readlane(ei, k)) * w1c[k];
            h16[(size_t)n * 64 + lane] = (unsigned short)f32_to_bf16(a);
        }
    }
    grid.sync();

    // ========== P5: agg + leaky + W2-dot; 2 nodes per wave (ILP x2) =========
    {
        int lane = t & 63;
        int wib  = t >> 6;
        int gw   = b * 16 + wib;
        const int nw = NBLK * 16;
        float w2   = W2[lane];
        float bias = b2[0];
        for (int p = gw; 2 * p < N_NODES; p += nw) {
            int n0 = 2 * p, n1 = 2 * p + 1;                 // N even -> n1 valid
            int i0 = row_start[n0], e0 = row_start[n0 + 1];
            int i1 = row_start[n1], e1 = row_start[n1 + 1];
            int d0 = e0 - i0, d1 = e1 - i1;
            float a0 = 0.f, a1 = 0.f;
            while (i0 + 3 < e0 && i1 + 3 < e1) {            // 8 gathers in flight
                int s00 = col[i0], s01 = col[i0+1], s02 = col[i0+2], s03 = col[i0+3];
                int s10 = col[i1], s11 = col[i1+1], s12 = col[i1+2], s13 = col[i1+3];
                float v00 = bf16_to_f32(h16[(size_t)s00 * 64 + lane]);
                float v01 = bf16_to_f32(h16[(size_t)s01 * 64 + lane]);
                float v02 = bf16_to_f32(h16[(size_t)s02 * 64 + lane]);
                float v03 = bf16_to_f32(h16[(size_t)s03 * 64 + lane]);
                float v10 = bf16_to_f32(h16[(size_t)s10 * 64 + lane]);
                float v11 = bf16_to_f32(h16[(size_t)s11 * 64 + lane]);
                float v12 = bf16_to_f32(h16[(size_t)s12 * 64 + lane]);
                float v13 = bf16_to_f32(h16[(size_t)s13 * 64 + lane]);
                a0 += (v00 + v01) + (v02 + v03);
                a1 += (v10 + v11) + (v12 + v13);
                i0 += 4; i1 += 4;
            }
            for (; i0 + 3 < e0; i0 += 4) {
                int s0 = col[i0], s1 = col[i0+1], s2 = col[i0+2], s3 = col[i0+3];
                float v0 = bf16_to_f32(h16[(size_t)s0 * 64 + lane]);
                float v1 = bf16_to_f32(h16[(size_t)s1 * 64 + lane]);
                float v2 = bf16_to_f32(h16[(size_t)s2 * 64 + lane]);
                float v3 = bf16_to_f32(h16[(size_t)s3 * 64 + lane]);
                a0 += (v0 + v1) + (v2 + v3);
            }
            for (; i0 < e0; ++i0) a0 += bf16_to_f32(h16[(size_t)col[i0] * 64 + lane]);
            for (; i1 + 3 < e1; i1 += 4) {
                int s0 = col[i1], s1 = col[i1+1], s2 = col[i1+2], s3 = col[i1+3];
                float v0 = bf16_to_f32(h16[(size_t)s0 * 64 + lane]);
                float v1 = bf16_to_f32(h16[(size_t)s1 * 64 + lane]);
                float v2 = bf16_to_f32(h16[(size_t)s2 * 64 + lane]);
                float v3 = bf16_to_f32(h16[(size_t)s3 * 64 + lane]);
                a1 += (v0 + v1) + (v2 + v3);
            }
            for (; i1 < e1; ++i1) a1 += bf16_to_f32(h16[(size_t)col[i1] * 64 + lane]);

            float x0 = a0 * rsqrtf(fmaxf((float)d0, 1.0f));
            float x1 = a1 * rsqrtf(fmaxf((float)d1, 1.0f));
            x0 = (x0 > 0.f) ? x0 : 0.01f * x0;
            x1 = (x1 > 0.f) ? x1 : 0.01f * x1;
            float p0 = x0 * w2, p1 = x1 * w2;
#pragma unroll
            for (int off = 32; off > 0; off >>= 1) {
                p0 += __shfl_xor(p0, off, 64);
                p1 += __shfl_xor(p1, off, 64);
            }
            if (lane == 0) { z[n0] = p0 + bias; z[n1] = p1 + bias; }
        }
    }
    grid.sync();

    // ================= P6: out[n] = sigmoid(sum z over in-edges) ============
    {
        int n = b * NTHR + t;       // 262144 threads >= N_NODES
        if (n < N_NODES) {
            int start = row_start[n], end = row_start[n + 1];
            float acc = 0.f;
            int i = start;
            for (; i + 3 < end; i += 4) {
                float a = z[col[i]],     bb = z[col[i + 1]];
                float c = z[col[i + 2]], d  = z[col[i + 3]];
                acc += (a + bb) + (c + d);
            }
            for (; i < end; ++i) acc += z[col[i]];
            out[n] = 1.0f / (1.0f + expf(-acc));
        }
    }
}

extern "C" void kernel_launch(void* const* d_in, const int* in_sizes, int n_in,
                              void* d_out, int out_size, void* d_ws, size_t ws_size,
                              hipStream_t stream) {
    const int* senders    = (const int*)d_in[1];
    const int* receivers  = (const int*)d_in[2];
    const float* emb      = (const float*)d_in[3];
    const float* W1       = (const float*)d_in[4];
    const float* W2       = (const float*)d_in[5];
    const float* b2       = (const float*)d_in[6];
    float* out            = (float*)d_out;

    char* ws = (char*)d_ws;
    unsigned*       ghist_s   = (unsigned*)(ws);
    unsigned*       ghist_r   = (unsigned*)(ws + 6400000);
    int*            coff      = (int*)(ws + 12800000);
    int*            pre_r     = (int*)(ws + 25600000);
    int*            row_start = (int*)(ws + 26000000);
    int*            gsum      = (int*)(ws + 26400016);
    int*            goff      = (int*)(ws + 26401040);
    float*          rs        = (float*)(ws + 26403200);
    int*            col       = (int*)(ws + 26803200);
    unsigned short* h16       = (unsigned short*)(ws + 30803200);
    float*          z         = (float*)(ws + 43603200);

    void* args[] = {
        (void*)&senders, (void*)&receivers, (void*)&emb, (void*)&W1,
        (void*)&W2, (void*)&b2, (void*)&ghist_s, (void*)&ghist_r,
        (void*)&coff, (void*)&pre_r, (void*)&row_start, (void*)&gsum,
        (void*)&goff, (void*)&rs, (void*)&col, (void*)&h16,
        (void*)&z, (void*)&out
    };
    hipLaunchCooperativeKernel((const void*)k_mega, dim3(NBLK), dim3(NTHR),
                               args, 0, stream);
}

// Round 11
// 213.560 us; speedup vs baseline: 1.9442x; 1.9442x over previous
//
#include <hip/hip_runtime.h>
#include <hip/hip_bf16.h>

#define N_NODES 100000
#define N_EDGES 1000000
#define SCAN_B 256
#define N_BLOCKS_SCAN ((N_NODES + SCAN_B - 1) / SCAN_B)   // 391

// superrange partitioning (hist/coff granularity)
#define RANGES 4
#define RSIZE  25000
#define RWORDS 12500          // u32 words (2 x u16 per word)
#define CHUNKS 32
#define CHUNK_EDGES (N_EDGES / CHUNKS)   // 31250
// fill granularity: 8 half-ranges
#define HRSIZE  12500
#define HRWORDS 6250

// ---------------- workspace layout (bytes) ---------------- (~44 MB)
// ghist_s   [0         .. 6,400,000)   u32[128*12500]
// ghist_r   [6,400,000 ..12,800,000)   u32[128*12500]
// coff      [12,800,000..25,600,000)   int[128*25000]
// cnt_r     [25,600,000..26,000,000)   int[N]
// row_start [26,000,000..26,400,016)   int[N+1]
// blockSums [26,400,016..26,401,580)   int[391]
// blockOffs [26,401,600..26,403,164)   int[391]
// rs        [26,403,200..26,803,200)   float[N]
// col       [26,803,200..30,803,200)   int[E]
// h16       [30,803,200..43,603,200)   ushort[N*64] bf16
// z         [43,603,200..44,003,200)   float[N]
// NO memset: every buffer densely overwritten before first read.

__device__ __forceinline__ unsigned f32_to_bf16(float v) {
    unsigned u = __float_as_uint(v);
    return (u + 0x7fffu + ((u >> 16) & 1u)) >> 16;     // RNE
}

// Histogram both index arrays into per-(arr,superrange,chunk) private copies.
__global__ void k_hist(const int* __restrict__ senders,
                       const int* __restrict__ receivers,
                       unsigned* __restrict__ ghist_s,
                       unsigned* __restrict__ ghist_r) {
    __shared__ unsigned lds[RWORDS];   // 50 KB
    int blk = blockIdx.x;              // [0, 256)
    int arr = blk >> 7;
    int rem = blk & 127;
    int r   = rem >> 5;
    int c   = rem & 31;
    const int* __restrict__ src = arr ? receivers : senders;
    unsigned* __restrict__ gh   = arr ? ghist_r : ghist_s;
    int t = threadIdx.x;

    for (int w = t; w < RWORDS; w += 1024) lds[w] = 0u;
    __syncthreads();

    int base = r * RSIZE;
    int beg  = c * CHUNK_EDGES;
    int end  = beg + CHUNK_EDGES;
    for (int i = beg + t; i < end; i += 1024) {
        unsigned idx = (unsigned)(src[i] - base);
        if (idx < (unsigned)RSIZE)
            atomicAdd(&lds[idx >> 1], 1u << ((idx & 1) * 16));
    }
    __syncthreads();

    unsigned* __restrict__ dst = gh + (size_t)rem * RWORDS;
    for (int w = t; w < RWORDS; w += 1024) dst[w] = lds[w];
}

// Merged reduce + scanA: per node, sum chunk copies -> cnt_r (recv) and
// rs (send); block-level inclusive scan of cnt -> blockSums.
__global__ void k_scanA2(const unsigned* __restrict__ ghist_s,
                         const unsigned* __restrict__ ghist_r,
                         int* __restrict__ cnt_r, float* __restrict__ rs,
                         int* __restrict__ blockSums) {
    __shared__ int s[SCAN_B];
    int t = threadIdx.x;
    int idx = blockIdx.x * SCAN_B + t;
    int v = 0;
    if (idx < N_NODES) {
        int r = idx / RSIZE;
        int bin = idx - r * RSIZE;
        int w = bin >> 1, sh = (bin & 1) * 16;
        const unsigned* __restrict__ gr = ghist_r + (size_t)(r * CHUNKS) * RWORDS + w;
        const unsigned* __restrict__ gs = ghist_s + (size_t)(r * CHUNKS) * RWORDS + w;
        unsigned sr_ = 0, ss_ = 0;
#pragma unroll
        for (int c = 0; c < CHUNKS; ++c) {
            sr_ += (gr[(size_t)c * RWORDS] >> sh) & 0xffffu;
            ss_ += (gs[(size_t)c * RWORDS] >> sh) & 0xffffu;
        }
        v = (int)sr_;
        cnt_r[idx] = v;
        rs[idx] = rsqrtf(fmaxf((float)ss_, 1.0f));
    }
    s[t] = v;
    __syncthreads();
    for (int off = 1; off < SCAN_B; off <<= 1) {
        int x = (t >= off) ? s[t - off] : 0;
        __syncthreads();
        s[t] += x;
        __syncthreads();
    }
    if (t == SCAN_B - 1) blockSums[blockIdx.x] = s[t];
}

__global__ void k_scanB(const int* __restrict__ blockSums, int* __restrict__ blockOffs) {
    __shared__ int s[512];
    int t = threadIdx.x;   // 512 threads, 1 block
    int v = (t < N_BLOCKS_SCAN) ? blockSums[t] : 0;
    s[t] = v;
    __syncthreads();
    for (int off = 1; off < 512; off <<= 1) {
        int x = (t >= off) ? s[t - off] : 0;
        __syncthreads();
        s[t] += x;
        __syncthreads();
    }
    if (t < N_BLOCKS_SCAN) blockOffs[t] = s[t] - v;   // exclusive
}

// Merged scanC + scan_chunks: row_start[] + per-(superrange,chunk,bin) coff[].
__global__ void k_scanCD(const int* __restrict__ cnt_r,
                         const int* __restrict__ blockOffs,
                         const unsigned* __restrict__ ghist_r,
                         int* __restrict__ row_start,
                         int* __restrict__ coff) {
    __shared__ int s[SCAN_B];
    int t = threadIdx.x;
    int idx = blockIdx.x * SCAN_B + t;
    int v = (idx < N_NODES) ? cnt_r[idx] : 0;
    s[t] = v;
    __syncthreads();
    for (int off = 1; off < SCAN_B; off <<= 1) {
        int x = (t >= off) ? s[t - off] : 0;
        __syncthreads();
        s[t] += x;
        __syncthreads();
    }
    if (idx < N_NODES) {
        int run = blockOffs[blockIdx.x] + s[t] - v;   // exclusive prefix
        row_start[idx] = run;
        int r = idx / RSIZE;
        int bin = idx - r * RSIZE;
        int w = bin >> 1, sh = (bin & 1) * 16;
        const unsigned* __restrict__ gr = ghist_r + (size_t)(r * CHUNKS) * RWORDS + w;
        int* __restrict__ co = coff + (size_t)(r * CHUNKS) * RSIZE + bin;
#pragma unroll
        for (int c = 0; c < CHUNKS; ++c) {
            co[(size_t)c * RSIZE] = run;
            run += (int)((gr[(size_t)c * RWORDS] >> sh) & 0xffffu);
        }
    }
    if (blockIdx.x == 0 && t == 0) row_start[N_NODES] = N_EDGES;
}

// Atomic-free CSR fill (8 half-ranges x 32 chunks = 256 blocks): LDS rank
// recompute + plain stores. Standalone so occupancy/VGPRs are its own.
__global__ void k_fill2(const int* __restrict__ senders,
                        const int* __restrict__ receivers,
                        const int* __restrict__ coff,
                        int* __restrict__ col) {
    __shared__ unsigned lds[HRWORDS];   // 25 KB
    int r8 = blockIdx.x >> 5;           // half-range 0..7
    int c  = blockIdx.x & 31;           // chunk 0..31
    int sr = r8 >> 1, hs = r8 & 1;
    int t  = threadIdx.x;

    for (int w = t; w < HRWORDS; w += 1024) lds[w] = 0u;
    __syncthreads();

    int base = r8 * HRSIZE;
    int beg  = c * CHUNK_EDGES, end = beg + CHUNK_EDGES;
    const int* __restrict__ co =
        coff + (size_t)(sr * CHUNKS + c) * RSIZE + hs * HRSIZE;
    for (int i = beg + t; i < end; i += 1024) {
        unsigned idx = (unsigned)(receivers[i] - base);
        if (idx < (unsigned)HRSIZE) {
            int sh = (idx & 1) * 16;
            unsigned old = atomicAdd(&lds[idx >> 1], 1u << sh);
            int rank = (int)((old >> sh) & 0xffffu);
            col[co[idx] + rank] = senders[i];
        }
    }
}

// Dense: h16[n][lane] = bf16( ((emb[n]*rs[n]) @ W1)[lane] )
// 256-thread blocks so w1c[64] stays in VGPRs (R9 lesson: 1024-thr spills).
__global__ void k_h(const float* __restrict__ emb,
                    const float* __restrict__ rs,
                    const float* __restrict__ W1,
                    unsigned short* __restrict__ h16) {
    int lane = threadIdx.x & 63;
    int wib  = threadIdx.x >> 6;
    int wpb  = blockDim.x >> 6;
    int gw   = blockIdx.x * wpb + wib;
    int nw   = gridDim.x * wpb;

    float w1c[64];
#pragma unroll
    for (int k = 0; k < 64; ++k) w1c[k] = W1[k * 64 + lane];

    for (int n = gw; n < N_NODES; n += nw) {
        float e = emb[(size_t)n * 64 + lane] * rs[n];
        float a = 0.f;
        int ei = __float_as_int(e);
#pragma unroll
        for (int k = 0; k < 64; ++k)
            a += __int_as_float(__builtin_amdgcn_readlane(ei, k)) * w1c[k];
        h16[(size_t)n * 64 + lane] = (unsigned short)f32_to_bf16(a);
    }
}

// Half-wave node mapping: lanes 0-31 -> node 2w, lanes 32-63 -> node 2w+1.
// Each lane loads ushort2 (2 bf16 features). 4-deep unroll per half-wave
// -> 8 outstanding gathers per wave; half the wave-task count of R8.
__global__ void k_agg_post(const int* __restrict__ row_start,
                           const int* __restrict__ col,
                           const unsigned* __restrict__ h32,   // h16 as u32 pairs
                           const float* __restrict__ W2,
                           const float* __restrict__ b2,
                           float* __restrict__ z) {
    int gtid = blockIdx.x * blockDim.x + threadIdx.x;
    int wid  = gtid >> 6;
    int lane = threadIdx.x & 63;
    int half = lane >> 5;              // which node of the pair
    int hl   = lane & 31;              // lane within half-wave
    int n = wid * 2 + half;
    if (n >= N_NODES) return;

    int start = row_start[n];
    int end   = row_start[n + 1];
    float a0 = 0.f, a1 = 0.f;          // features 2*hl, 2*hl+1
    int i = start;
    for (; i + 3 < end; i += 4) {
        int s0 = col[i], s1 = col[i + 1], s2 = col[i + 2], s3 = col[i + 3];
        unsigned u0 = h32[(size_t)s0 * 32 + hl];
        unsigned u1 = h32[(size_t)s1 * 32 + hl];
        unsigned u2 = h32[(size_t)s2 * 32 + hl];
        unsigned u3 = h32[(size_t)s3 * 32 + hl];
        a0 += (__uint_as_float(u0 << 16) + __uint_as_float(u1 << 16)) +
              (__uint_as_float(u2 << 16) + __uint_as_float(u3 << 16));
        a1 += (__uint_as_float(u0 & 0xffff0000u) + __uint_as_float(u1 & 0xffff0000u)) +
              (__uint_as_float(u2 & 0xffff0000u) + __uint_as_float(u3 & 0xffff0000u));
    }
    for (; i < end; ++i) {
        unsigned u = h32[(size_t)col[i] * 32 + hl];
        a0 += __uint_as_float(u << 16);
        a1 += __uint_as_float(u & 0xffff0000u);
    }

    float rsq = rsqrtf(fmaxf((float)(end - start), 1.0f));
    float x0 = a0 * rsq, x1 = a1 * rsq;
    x0 = (x0 > 0.f) ? x0 : 0.01f * x0;
    x1 = (x1 > 0.f) ? x1 : 0.01f * x1;
    float2 w2 = ((const float2*)W2)[hl];
    float p = x0 * w2.x + x1 * w2.y;
#pragma unroll
    for (int off = 16; off > 0; off >>= 1) p += __shfl_xor(p, off, 64);
    if (hl == 0) z[n] = p + b2[0];
}

// thread per node: out[n] = sigmoid( sum over in-edges z[s] )  (z L2-resident)
__global__ void k_agg2_sigmoid(const int* __restrict__ row_start,
                               const int* __restrict__ col,
                               const float* __restrict__ z,
                               float* __restrict__ out) {
    int n = blockIdx.x * blockDim.x + threadIdx.x;
    if (n >= N_NODES) return;
    int start = row_start[n];
    int end   = row_start[n + 1];
    float acc = 0.f;
    int i = start;
    for (; i + 3 < end; i += 4) {
        float a = z[col[i]],     b = z[col[i + 1]];
        float c = z[col[i + 2]], d = z[col[i + 3]];
        acc += (a + b) + (c + d);
    }
    for (; i < end; ++i) acc += z[col[i]];
    out[n] = 1.0f / (1.0f + expf(-acc));
}

extern "C" void kernel_launch(void* const* d_in, const int* in_sizes, int n_in,
                              void* d_out, int out_size, void* d_ws, size_t ws_size,
                              hipStream_t stream) {
    const int* senders    = (const int*)d_in[1];
    const int* receivers  = (const int*)d_in[2];
    const float* emb      = (const float*)d_in[3];
    const float* W1       = (const float*)d_in[4];
    const float* W2       = (const float*)d_in[5];
    const float* b2       = (const float*)d_in[6];
    float* out            = (float*)d_out;

    char* ws = (char*)d_ws;
    unsigned*       ghist_s   = (unsigned*)(ws);
    unsigned*       ghist_r   = (unsigned*)(ws + 6400000);
    int*            coff      = (int*)(ws + 12800000);
    int*            cnt_r     = (int*)(ws + 25600000);
    int*            row_start = (int*)(ws + 26000000);
    int*            blockSums = (int*)(ws + 26400016);
    int*            blockOffs = (int*)(ws + 26401600);
    float*          rs        = (float*)(ws + 26403200);
    int*            col       = (int*)(ws + 26803200);
    unsigned short* h16       = (unsigned short*)(ws + 30803200);
    float*          z         = (float*)(ws + 43603200);

    const int B = 256;
    k_hist<<<2 * RANGES * CHUNKS, 1024, 0, stream>>>(senders, receivers, ghist_s, ghist_r);
    k_scanA2<<<N_BLOCKS_SCAN, SCAN_B, 0, stream>>>(ghist_s, ghist_r, cnt_r, rs, blockSums);
    k_scanB<<<1, 512, 0, stream>>>(blockSums, blockOffs);
    k_scanCD<<<N_BLOCKS_SCAN, SCAN_B, 0, stream>>>(cnt_r, blockOffs, ghist_r, row_start, coff);
    k_fill2<<<RANGES * CHUNKS * 2, 1024, 0, stream>>>(senders, receivers, coff, col);
    k_h<<<2048, 256, 0, stream>>>(emb, rs, W1, h16);
    // 2 nodes per wave -> 50000 waves -> 12500 blocks of 256
    k_agg_post<<<12500, B, 0, stream>>>(row_start, col, (const unsigned*)h16, W2, b2, z);
    k_agg2_sigmoid<<<(N_NODES + B - 1) / B, B, 0, stream>>>(row_start, col, z, out);
}

// Round 12
// 210.652 us; speedup vs baseline: 1.9710x; 1.0138x over previous
//
#include <hip/hip_runtime.h>
#include <hip/hip_bf16.h>

#define N_NODES 100000
#define N_EDGES 1000000
#define SCAN_B 256
#define N_BLOCKS_SCAN ((N_NODES + SCAN_B - 1) / SCAN_B)   // 391

// superrange partitioning (hist/coff granularity)
#define RANGES 4
#define RSIZE  25000
#define RWORDS 12500          // u32 words (2 x u16 per word)
#define CHUNKS 32
#define CHUNK_EDGES (N_EDGES / CHUNKS)   // 31250
// fill granularity: 8 half-ranges
#define HRSIZE  12500
#define HRWORDS 6250

// ---------------- workspace layout (bytes) ---------------- (~44 MB)
// ghist_s   [0         .. 6,400,000)   u32[128*12500]
// ghist_r   [6,400,000 ..12,800,000)   u32[128*12500]
// coff      [12,800,000..25,600,000)   int[128*25000]
// cnt_r     [25,600,000..26,000,000)   int[N]
// row_start [26,000,000..26,400,016)   int[N+1]
// blockSums [26,400,016..26,401,580)   int[391]
// rs        [26,403,200..26,803,200)   float[N]
// col       [26,803,200..30,803,200)   int[E]
// h16       [30,803,200..43,603,200)   ushort[N*64] bf16
// z         [43,603,200..44,003,200)   float[N]
// NO memset: every buffer densely overwritten before first read.

__device__ __forceinline__ unsigned f32_to_bf16(float v) {
    unsigned u = __float_as_uint(v);
    return (u + 0x7fffu + ((u >> 16) & 1u)) >> 16;     // RNE
}

// Histogram both index arrays into per-(arr,superrange,chunk) private copies.
__global__ void k_hist(const int* __restrict__ senders,
                       const int* __restrict__ receivers,
                       unsigned* __restrict__ ghist_s,
                       unsigned* __restrict__ ghist_r) {
    __shared__ unsigned lds[RWORDS];   // 50 KB
    int blk = blockIdx.x;              // [0, 256)
    int arr = blk >> 7;
    int rem = blk & 127;
    int r   = rem >> 5;
    int c   = rem & 31;
    const int* __restrict__ src = arr ? receivers : senders;
    unsigned* __restrict__ gh   = arr ? ghist_r : ghist_s;
    int t = threadIdx.x;

    for (int w = t; w < RWORDS; w += 1024) lds[w] = 0u;
    __syncthreads();

    int base = r * RSIZE;
    int beg  = c * CHUNK_EDGES;
    int end  = beg + CHUNK_EDGES;
    for (int i = beg + t; i < end; i += 1024) {
        unsigned idx = (unsigned)(src[i] - base);
        if (idx < (unsigned)RSIZE)
            atomicAdd(&lds[idx >> 1], 1u << ((idx & 1) * 16));
    }
    __syncthreads();

    unsigned* __restrict__ dst = gh + (size_t)rem * RWORDS;
    for (int w = t; w < RWORDS; w += 1024) dst[w] = lds[w];
}

// Merged reduce + scanA: per node, sum chunk copies -> cnt_r (recv) and
// rs (send); block-level inclusive scan of cnt -> blockSums.
__global__ void k_scanA2(const unsigned* __restrict__ ghist_s,
                         const unsigned* __restrict__ ghist_r,
                         int* __restrict__ cnt_r, float* __restrict__ rs,
                         int* __restrict__ blockSums) {
    __shared__ int s[SCAN_B];
    int t = threadIdx.x;
    int idx = blockIdx.x * SCAN_B + t;
    int v = 0;
    if (idx < N_NODES) {
        int r = idx / RSIZE;
        int bin = idx - r * RSIZE;
        int w = bin >> 1, sh = (bin & 1) * 16;
        const unsigned* __restrict__ gr = ghist_r + (size_t)(r * CHUNKS) * RWORDS + w;
        const unsigned* __restrict__ gs = ghist_s + (size_t)(r * CHUNKS) * RWORDS + w;
        unsigned sr_ = 0, ss_ = 0;
#pragma unroll
        for (int c = 0; c < CHUNKS; ++c) {
            sr_ += (gr[(size_t)c * RWORDS] >> sh) & 0xffffu;
            ss_ += (gs[(size_t)c * RWORDS] >> sh) & 0xffffu;
        }
        v = (int)sr_;
        cnt_r[idx] = v;
        rs[idx] = rsqrtf(fmaxf((float)ss_, 1.0f));
    }
    s[t] = v;
    __syncthreads();
    for (int off = 1; off < SCAN_B; off <<= 1) {
        int x = (t >= off) ? s[t - off] : 0;
        __syncthreads();
        s[t] += x;
        __syncthreads();
    }
    if (t == SCAN_B - 1) blockSums[blockIdx.x] = s[t];
}

// scanC + scan_chunks + inline global offset (replaces k_scanB):
// each block sums blockSums[0..b) itself, then emits row_start[] + coff[].
__global__ void k_scanCD(const int* __restrict__ cnt_r,
                         const int* __restrict__ blockSums,
                         const unsigned* __restrict__ ghist_r,
                         int* __restrict__ row_start,
                         int* __restrict__ coff) {
    __shared__ int s[SCAN_B];
    int t = threadIdx.x;
    int b = blockIdx.x;

    // ---- block offset = sum of blockSums[0..b) ----
    int acc = 0;
    for (int j = t; j < b; j += SCAN_B) acc += blockSums[j];
    s[t] = acc;
    __syncthreads();
    for (int off = SCAN_B / 2; off > 0; off >>= 1) {
        if (t < off) s[t] += s[t + off];
        __syncthreads();
    }
    int blockOff = s[0];
    __syncthreads();

    // ---- inclusive scan of this block's counts ----
    int idx = b * SCAN_B + t;
    int v = (idx < N_NODES) ? cnt_r[idx] : 0;
    s[t] = v;
    __syncthreads();
    for (int off = 1; off < SCAN_B; off <<= 1) {
        int x = (t >= off) ? s[t - off] : 0;
        __syncthreads();
        s[t] += x;
        __syncthreads();
    }
    if (idx < N_NODES) {
        int run = blockOff + s[t] - v;   // exclusive prefix
        row_start[idx] = run;
        int r = idx / RSIZE;
        int bin = idx - r * RSIZE;
        int w = bin >> 1, sh = (bin & 1) * 16;
        const unsigned* __restrict__ gr = ghist_r + (size_t)(r * CHUNKS) * RWORDS + w;
        int* __restrict__ co = coff + (size_t)(r * CHUNKS) * RSIZE + bin;
#pragma unroll
        for (int c = 0; c < CHUNKS; ++c) {
            co[(size_t)c * RSIZE] = run;
            run += (int)((gr[(size_t)c * RWORDS] >> sh) & 0xffffu);
        }
    }
    if (b == 0 && t == 0) row_start[N_NODES] = N_EDGES;
}

// Atomic-free CSR fill (8 half-ranges x 32 chunks = 256 blocks): LDS rank
// recompute + plain stores.
__global__ void k_fill2(const int* __restrict__ senders,
                        const int* __restrict__ receivers,
                        const int* __restrict__ coff,
                        int* __restrict__ col) {
    __shared__ unsigned lds[HRWORDS];   // 25 KB
    int r8 = blockIdx.x >> 5;           // half-range 0..7
    int c  = blockIdx.x & 31;           // chunk 0..31
    int sr = r8 >> 1, hs = r8 & 1;
    int t  = threadIdx.x;

    for (int w = t; w < HRWORDS; w += 1024) lds[w] = 0u;
    __syncthreads();

    int base = r8 * HRSIZE;
    int beg  = c * CHUNK_EDGES, end = beg + CHUNK_EDGES;
    const int* __restrict__ co =
        coff + (size_t)(sr * CHUNKS + c) * RSIZE + hs * HRSIZE;
    for (int i = beg + t; i < end; i += 1024) {
        unsigned idx = (unsigned)(receivers[i] - base);
        if (idx < (unsigned)HRSIZE) {
            int sh = (idx & 1) * 16;
            unsigned old = atomicAdd(&lds[idx >> 1], 1u << sh);
            int rank = (int)((old >> sh) & 0xffffu);
            col[co[idx] + rank] = senders[i];
        }
    }
}

// Dense: h16[n][lane] = bf16( ((emb[n]*rs[n]) @ W1)[lane] )
// 256-thread blocks so w1c[64] stays in VGPRs.
__global__ void k_h(const float* __restrict__ emb,
                    const float* __restrict__ rs,
                    const float* __restrict__ W1,
                    unsigned short* __restrict__ h16) {
    int lane = threadIdx.x & 63;
    int wib  = threadIdx.x >> 6;
    int wpb  = blockDim.x >> 6;
    int gw   = blockIdx.x * wpb + wib;
    int nw   = gridDim.x * wpb;

    float w1c[64];
#pragma unroll
    for (int k = 0; k < 64; ++k) w1c[k] = W1[k * 64 + lane];

    for (int n = gw; n < N_NODES; n += nw) {
        float e = emb[(size_t)n * 64 + lane] * rs[n];
        float a = 0.f;
        int ei = __float_as_int(e);
#pragma unroll
        for (int k = 0; k < 64; ++k)
            a += __int_as_float(__builtin_amdgcn_readlane(ei, k)) * w1c[k];
        h16[(size_t)n * 64 + lane] = (unsigned short)f32_to_bf16(a);
    }
}

// Quarter-wave node mapping: 16 lanes per node, 4 nodes per wave.
// Each lane loads uint2 (4 bf16 features 4*hl..4*hl+3); 4-deep unroll
// -> 16 outstanding gathers per wave; quarter the wave-task count of R8.
__global__ void k_agg_post(const int* __restrict__ row_start,
                           const int* __restrict__ col,
                           const uint2* __restrict__ h2,   // h16 rows as 16 x uint2
                           const float* __restrict__ W2,
                           const float* __restrict__ b2,
                           float* __restrict__ z) {
    int gtid = blockIdx.x * blockDim.x + threadIdx.x;
    int wid  = gtid >> 6;
    int lane = threadIdx.x & 63;
    int q    = lane >> 4;              // node slot 0..3
    int hl   = lane & 15;              // lane within quarter-wave
    int n = wid * 4 + q;               // grid sized so n < N_NODES always
    if (n >= N_NODES) return;

    int start = row_start[n];
    int end   = row_start[n + 1];
    float a0 = 0.f, a1 = 0.f, a2 = 0.f, a3 = 0.f;   // features 4hl..4hl+3
    int i = start;
    for (; i + 3 < end; i += 4) {
        int s0 = col[i], s1 = col[i + 1], s2 = col[i + 2], s3 = col[i + 3];
        uint2 u0 = h2[(size_t)s0 * 16 + hl];
        uint2 u1 = h2[(size_t)s1 * 16 + hl];
        uint2 u2 = h2[(size_t)s2 * 16 + hl];
        uint2 u3 = h2[(size_t)s3 * 16 + hl];
        a0 += (__uint_as_float(u0.x << 16) + __uint_as_float(u1.x << 16)) +
              (__uint_as_float(u2.x << 16) + __uint_as_float(u3.x << 16));
        a1 += (__uint_as_float(u0.x & 0xffff0000u) + __uint_as_float(u1.x & 0xffff0000u)) +
              (__uint_as_float(u2.x & 0xffff0000u) + __uint_as_float(u3.x & 0xffff0000u));
        a2 += (__uint_as_float(u0.y << 16) + __uint_as_float(u1.y << 16)) +
              (__uint_as_float(u2.y << 16) + __uint_as_float(u3.y << 16));
        a3 += (__uint_as_float(u0.y & 0xffff0000u) + __uint_as_float(u1.y & 0xffff0000u)) +
              (__uint_as_float(u2.y & 0xffff0000u) + __uint_as_float(u3.y & 0xffff0000u));
    }
    for (; i < end; ++i) {
        uint2 u = h2[(size_t)col[i] * 16 + hl];
        a0 += __uint_as_float(u.x << 16);
        a1 += __uint_as_float(u.x & 0xffff0000u);
        a2 += __uint_as_float(u.y << 16);
        a3 += __uint_as_float(u.y & 0xffff0000u);
    }

    float rsq = rsqrtf(fmaxf((float)(end - start), 1.0f));
    float x0 = a0 * rsq, x1 = a1 * rsq, x2 = a2 * rsq, x3 = a3 * rsq;
    x0 = (x0 > 0.f) ? x0 : 0.01f * x0;
    x1 = (x1 > 0.f) ? x1 : 0.01f * x1;
    x2 = (x2 > 0.f) ? x2 : 0.01f * x2;
    x3 = (x3 > 0.f) ? x3 : 0.01f * x3;
    float4 w2 = ((const float4*)W2)[hl];
    float p = (x0 * w2.x + x1 * w2.y) + (x2 * w2.z + x3 * w2.w);
#pragma unroll
    for (int off = 8; off > 0; off >>= 1) p += __shfl_xor(p, off, 64);
    if (hl == 0) z[n] = p + b2[0];
}

// thread per node: out[n] = sigmoid( sum over in-edges z[s] )  (z L2-resident)
__global__ void k_agg2_sigmoid(const int* __restrict__ row_start,
                               const int* __restrict__ col,
                               const float* __restrict__ z,
                               float* __restrict__ out) {
    int n = blockIdx.x * blockDim.x + threadIdx.x;
    if (n >= N_NODES) return;
    int start = row_start[n];
    int end   = row_start[n + 1];
    float acc = 0.f;
    int i = start;
    for (; i + 3 < end; i += 4) {
        float a = z[col[i]],     b = z[col[i + 1]];
        float c = z[col[i + 2]], d = z[col[i + 3]];
        acc += (a + b) + (c + d);
    }
    for (; i < end; ++i) acc += z[col[i]];
    out[n] = 1.0f / (1.0f + expf(-acc));
}

extern "C" void kernel_launch(void* const* d_in, const int* in_sizes, int n_in,
                              void* d_out, int out_size, void* d_ws, size_t ws_size,
                              hipStream_t stream) {
    const int* senders    = (const int*)d_in[1];
    const int* receivers  = (const int*)d_in[2];
    const float* emb      = (const float*)d_in[3];
    const float* W1       = (const float*)d_in[4];
    const float* W2       = (const float*)d_in[5];
    const float* b2       = (const float*)d_in[6];
    float* out            = (float*)d_out;

    char* ws = (char*)d_ws;
    unsigned*       ghist_s   = (unsigned*)(ws);
    unsigned*       ghist_r   = (unsigned*)(ws + 6400000);
    int*            coff      = (int*)(ws + 12800000);
    int*            cnt_r     = (int*)(ws + 25600000);
    int*            row_start = (int*)(ws + 26000000);
    int*            blockSums = (int*)(ws + 26400016);
    float*          rs        = (float*)(ws + 26403200);
    int*            col       = (int*)(ws + 26803200);
    unsigned short* h16       = (unsigned short*)(ws + 30803200);
    float*          z         = (float*)(ws + 43603200);

    const int B = 256;
    k_hist<<<2 * RANGES * CHUNKS, 1024, 0, stream>>>(senders, receivers, ghist_s, ghist_r);
    k_scanA2<<<N_BLOCKS_SCAN, SCAN_B, 0, stream>>>(ghist_s, ghist_r, cnt_r, rs, blockSums);
    k_scanCD<<<N_BLOCKS_SCAN, SCAN_B, 0, stream>>>(cnt_r, blockSums, ghist_r, row_start, coff);
    k_fill2<<<RANGES * CHUNKS * 2, 1024, 0, stream>>>(senders, receivers, coff, col);
    k_h<<<2048, 256, 0, stream>>>(emb, rs, W1, h16);
    // 4 nodes per wave -> 25000 waves -> 6250 blocks of 256
    k_agg_post<<<6250, B, 0, stream>>>(row_start, col, (const uint2*)h16, W2, b2, z);
    k_agg2_sigmoid<<<(N_NODES + B - 1) / B, B, 0, stream>>>(row_start, col, z, out);
}

// Round 13
// 209.611 us; speedup vs baseline: 1.9808x; 1.0050x over previous
//
#include <hip/hip_runtime.h>
#include <hip/hip_bf16.h>

#define N_NODES 100000
#define N_EDGES 1000000
#define SCAN_B 256
#define N_BLOCKS_SCAN ((N_NODES + SCAN_B - 1) / SCAN_B)   // 391
#define H_BLOCKS 1024

// superrange partitioning (hist/coff granularity)
#define RANGES 4
#define RSIZE  25000
#define RWORDS 12500          // u32 words (2 x u16 per word)
#define CHUNKS 32
#define CHUNK_EDGES (N_EDGES / CHUNKS)   // 31250
// fill granularity: 8 half-ranges
#define HRSIZE  12500
#define HRWORDS 6250

// ---------------- workspace layout (bytes) ---------------- (~44 MB)
// ghist_s   [0         .. 6,400,000)   u32[128*12500]
// ghist_r   [6,400,000 ..12,800,000)   u32[128*12500]
// coff      [12,800,000..25,600,000)   int[128*25000]
// cnt_r     [25,600,000..26,000,000)   int[N]
// row_start [26,000,000..26,400,016)   int[N+1]
// blockSums [26,400,016..26,401,580)   int[391]
// rs        [26,403,200..26,803,200)   float[N]
// col       [26,803,200..30,803,200)   int[E]
// h16       [30,803,200..43,603,200)   ushort[N*64] bf16
// z         [43,603,200..44,003,200)   float[N]
// NO memset: every buffer densely overwritten before first read.

__device__ __forceinline__ unsigned f32_to_bf16(float v) {
    unsigned u = __float_as_uint(v);
    return (u + 0x7fffu + ((u >> 16) & 1u)) >> 16;     // RNE
}

// Histogram both index arrays into per-(arr,superrange,chunk) private copies.
__global__ void k_hist(const int* __restrict__ senders,
                       const int* __restrict__ receivers,
                       unsigned* __restrict__ ghist_s,
                       unsigned* __restrict__ ghist_r) {
    __shared__ unsigned lds[RWORDS];   // 50 KB
    int blk = blockIdx.x;              // [0, 256)
    int arr = blk >> 7;
    int rem = blk & 127;
    int r   = rem >> 5;
    int c   = rem & 31;
    const int* __restrict__ src = arr ? receivers : senders;
    unsigned* __restrict__ gh   = arr ? ghist_r : ghist_s;
    int t = threadIdx.x;

    for (int w = t; w < RWORDS; w += 1024) lds[w] = 0u;
    __syncthreads();

    int base = r * RSIZE;
    int beg  = c * CHUNK_EDGES;
    int end  = beg + CHUNK_EDGES;
    for (int i = beg + t; i < end; i += 1024) {
        unsigned idx = (unsigned)(src[i] - base);
        if (idx < (unsigned)RSIZE)
            atomicAdd(&lds[idx >> 1], 1u << ((idx & 1) * 16));
    }
    __syncthreads();

    unsigned* __restrict__ dst = gh + (size_t)rem * RWORDS;
    for (int w = t; w < RWORDS; w += 1024) dst[w] = lds[w];
}

// Merged reduce + scanA: per node, sum chunk copies -> cnt_r (recv) and
// rs (send); block-level inclusive scan of cnt -> blockSums.
__global__ void k_scanA2(const unsigned* __restrict__ ghist_s,
                         const unsigned* __restrict__ ghist_r,
                         int* __restrict__ cnt_r, float* __restrict__ rs,
                         int* __restrict__ blockSums) {
    __shared__ int s[SCAN_B];
    int t = threadIdx.x;
    int idx = blockIdx.x * SCAN_B + t;
    int v = 0;
    if (idx < N_NODES) {
        int r = idx / RSIZE;
        int bin = idx - r * RSIZE;
        int w = bin >> 1, sh = (bin & 1) * 16;
        const unsigned* __restrict__ gr = ghist_r + (size_t)(r * CHUNKS) * RWORDS + w;
        const unsigned* __restrict__ gs = ghist_s + (size_t)(r * CHUNKS) * RWORDS + w;
        unsigned sr_ = 0, ss_ = 0;
#pragma unroll
        for (int c = 0; c < CHUNKS; ++c) {
            sr_ += (gr[(size_t)c * RWORDS] >> sh) & 0xffffu;
            ss_ += (gs[(size_t)c * RWORDS] >> sh) & 0xffffu;
        }
        v = (int)sr_;
        cnt_r[idx] = v;
        rs[idx] = rsqrtf(fmaxf((float)ss_, 1.0f));
    }
    s[t] = v;
    __syncthreads();
    for (int off = 1; off < SCAN_B; off <<= 1) {
        int x = (t >= off) ? s[t - off] : 0;
        __syncthreads();
        s[t] += x;
        __syncthreads();
    }
    if (t == SCAN_B - 1) blockSums[blockIdx.x] = s[t];
}

// Merged kernel: blocks [0, 391) = scanCD (row_start + coff, with inline
// global offset); blocks [391, 391+H_BLOCKS) = k_h (dense MLP layer 1).
// Both only depend on k_scanA2 outputs; 256-thr blocks keep w1c in VGPRs.
__global__ void k_scanCD_h(const int* __restrict__ cnt_r,
                           const int* __restrict__ blockSums,
                           const unsigned* __restrict__ ghist_r,
                           int* __restrict__ row_start,
                           int* __restrict__ coff,
                           const float* __restrict__ emb,
                           const float* __restrict__ rs,
                           const float* __restrict__ W1,
                           unsigned short* __restrict__ h16) {
    __shared__ int s[SCAN_B];
    int t = threadIdx.x;
    int b = blockIdx.x;

    if (b < N_BLOCKS_SCAN) {
        // ---- block offset = sum of blockSums[0..b) ----
        int acc = 0;
        for (int j = t; j < b; j += SCAN_B) acc += blockSums[j];
        s[t] = acc;
        __syncthreads();
        for (int off = SCAN_B / 2; off > 0; off >>= 1) {
            if (t < off) s[t] += s[t + off];
            __syncthreads();
        }
        int blockOff = s[0];
        __syncthreads();

        // ---- inclusive scan of this block's counts ----
        int idx = b * SCAN_B + t;
        int v = (idx < N_NODES) ? cnt_r[idx] : 0;
        s[t] = v;
        __syncthreads();
        for (int off = 1; off < SCAN_B; off <<= 1) {
            int x = (t >= off) ? s[t - off] : 0;
            __syncthreads();
            s[t] += x;
            __syncthreads();
        }
        if (idx < N_NODES) {
            int run = blockOff + s[t] - v;   // exclusive prefix
            row_start[idx] = run;
            int r = idx / RSIZE;
            int bin = idx - r * RSIZE;
            int w = bin >> 1, sh = (bin & 1) * 16;
            const unsigned* __restrict__ gr = ghist_r + (size_t)(r * CHUNKS) * RWORDS + w;
            int* __restrict__ co = coff + (size_t)(r * CHUNKS) * RSIZE + bin;
#pragma unroll
            for (int c = 0; c < CHUNKS; ++c) {
                co[(size_t)c * RSIZE] = run;
                run += (int)((gr[(size_t)c * RWORDS] >> sh) & 0xffffu);
            }
        }
        if (b == 0 && t == 0) row_start[N_NODES] = N_EDGES;
    } else {
        // ---- h16[n][lane] = bf16( ((emb[n]*rs[n]) @ W1)[lane] ) ----
        int lane = t & 63;
        int wib  = t >> 6;                          // 0..3
        int gw   = (b - N_BLOCKS_SCAN) * 4 + wib;   // 4096 waves
        const int nw = H_BLOCKS * 4;

        float w1c[64];
#pragma unroll
        for (int k = 0; k < 64; ++k) w1c[k] = W1[k * 64 + lane];

        for (int n = gw; n < N_NODES; n += nw) {
            float e = emb[(size_t)n * 64 + lane] * rs[n];
            float a = 0.f;
            int ei = __float_as_int(e);
#pragma unroll
            for (int k = 0; k < 64; ++k)
                a += __int_as_float(__builtin_amdgcn_readlane(ei, k)) * w1c[k];
            h16[(size_t)n * 64 + lane] = (unsigned short)f32_to_bf16(a);
        }
    }
}

// Atomic-free CSR fill (8 half-ranges x 32 chunks = 256 blocks): LDS rank
// recompute + plain stores.
__global__ void k_fill2(const int* __restrict__ senders,
                        const int* __restrict__ receivers,
                        const int* __restrict__ coff,
                        int* __restrict__ col) {
    __shared__ unsigned lds[HRWORDS];   // 25 KB
    int r8 = blockIdx.x >> 5;           // half-range 0..7
    int c  = blockIdx.x & 31;           // chunk 0..31
    int sr = r8 >> 1, hs = r8 & 1;
    int t  = threadIdx.x;

    for (int w = t; w < HRWORDS; w += 1024) lds[w] = 0u;
    __syncthreads();

    int base = r8 * HRSIZE;
    int beg  = c * CHUNK_EDGES, end = beg + CHUNK_EDGES;
    const int* __restrict__ co =
        coff + (size_t)(sr * CHUNKS + c) * RSIZE + hs * HRSIZE;
    for (int i = beg + t; i < end; i += 1024) {
        unsigned idx = (unsigned)(receivers[i] - base);
        if (idx < (unsigned)HRSIZE) {
            int sh = (idx & 1) * 16;
            unsigned old = atomicAdd(&lds[idx >> 1], 1u << sh);
            int rank = (int)((old >> sh) & 0xffffu);
            col[co[idx] + rank] = senders[i];
        }
    }
}

// Half-wave node mapping (R11's best-measured config): lanes 0-31 -> node 2w,
// lanes 32-63 -> node 2w+1. Each lane loads ushort2 (2 bf16 features);
// 4-deep unroll -> 8 outstanding gathers per wave.
__global__ void k_agg_post(const int* __restrict__ row_start,
                           const int* __restrict__ col,
                           const unsigned* __restrict__ h32,   // h16 as u32 pairs
                           const float* __restrict__ W2,
                           const float* __restrict__ b2,
                           float* __restrict__ z) {
    int gtid = blockIdx.x * blockDim.x + threadIdx.x;
    int wid  = gtid >> 6;
    int lane = threadIdx.x & 63;
    int half = lane >> 5;              // which node of the pair
    int hl   = lane & 31;              // lane within half-wave
    int n = wid * 2 + half;
    if (n >= N_NODES) return;

    int start = row_start[n];
    int end   = row_start[n + 1];
    float a0 = 0.f, a1 = 0.f;          // features 2*hl, 2*hl+1
    int i = start;
    for (; i + 3 < end; i += 4) {
        int s0 = col[i], s1 = col[i + 1], s2 = col[i + 2], s3 = col[i + 3];
        unsigned u0 = h32[(size_t)s0 * 32 + hl];
        unsigned u1 = h32[(size_t)s1 * 32 + hl];
        unsigned u2 = h32[(size_t)s2 * 32 + hl];
        unsigned u3 = h32[(size_t)s3 * 32 + hl];
        a0 += (__uint_as_float(u0 << 16) + __uint_as_float(u1 << 16)) +
              (__uint_as_float(u2 << 16) + __uint_as_float(u3 << 16));
        a1 += (__uint_as_float(u0 & 0xffff0000u) + __uint_as_float(u1 & 0xffff0000u)) +
              (__uint_as_float(u2 & 0xffff0000u) + __uint_as_float(u3 & 0xffff0000u));
    }
    for (; i < end; ++i) {
        unsigned u = h32[(size_t)col[i] * 32 + hl];
        a0 += __uint_as_float(u << 16);
        a1 += __uint_as_float(u & 0xffff0000u);
    }

    float rsq = rsqrtf(fmaxf((float)(end - start), 1.0f));
    float x0 = a0 * rsq, x1 = a1 * rsq;
    x0 = (x0 > 0.f) ? x0 : 0.01f * x0;
    x1 = (x1 > 0.f) ? x1 : 0.01f * x1;
    float2 w2 = ((const float2*)W2)[hl];
    float p = x0 * w2.x + x1 * w2.y;
#pragma unroll
    for (int off = 16; off > 0; off >>= 1) p += __shfl_xor(p, off, 64);
    if (hl == 0) z[n] = p + b2[0];
}

// thread per node: out[n] = sigmoid( sum over in-edges z[s] )  (z L2-resident)
__global__ void k_agg2_sigmoid(const int* __restrict__ row_start,
                               const int* __restrict__ col,
                               const float* __restrict__ z,
                               float* __restrict__ out) {
    int n = blockIdx.x * blockDim.x + threadIdx.x;
    if (n >= N_NODES) return;
    int start = row_start[n];
    int end   = row_start[n + 1];
    float acc = 0.f;
    int i = start;
    for (; i + 3 < end; i += 4) {
        float a = z[col[i]],     b = z[col[i + 1]];
        float c = z[col[i + 2]], d = z[col[i + 3]];
        acc += (a + b) + (c + d);
    }
    for (; i < end; ++i) acc += z[col[i]];
    out[n] = 1.0f / (1.0f + expf(-acc));
}

extern "C" void kernel_launch(void* const* d_in, const int* in_sizes, int n_in,
                              void* d_out, int out_size, void* d_ws, size_t ws_size,
                              hipStream_t stream) {
    const int* senders    = (const int*)d_in[1];
    const int* receivers  = (const int*)d_in[2];
    const float* emb      = (const float*)d_in[3];
    const float* W1       = (const float*)d_in[4];
    const float* W2       = (const float*)d_in[5];
    const float* b2       = (const float*)d_in[6];
    float* out            = (float*)d_out;

    char* ws = (char*)d_ws;
    unsigned*       ghist_s   = (unsigned*)(ws);
    unsigned*       ghist_r   = (unsigned*)(ws + 6400000);
    int*            coff      = (int*)(ws + 12800000);
    int*            cnt_r     = (int*)(ws + 25600000);
    int*            row_start = (int*)(ws + 26000000);
    int*            blockSums = (int*)(ws + 26400016);
    float*          rs        = (float*)(ws + 26403200);
    int*            col       = (int*)(ws + 26803200);
    unsigned short* h16       = (unsigned short*)(ws + 30803200);
    float*          z         = (float*)(ws + 43603200);

    const int B = 256;
    k_hist<<<2 * RANGES * CHUNKS, 1024, 0, stream>>>(senders, receivers, ghist_s, ghist_r);
    k_scanA2<<<N_BLOCKS_SCAN, SCAN_B, 0, stream>>>(ghist_s, ghist_r, cnt_r, rs, blockSums);
    k_scanCD_h<<<N_BLOCKS_SCAN + H_BLOCKS, B, 0, stream>>>(
        cnt_r, blockSums, ghist_r, row_start, coff, emb, rs, W1, h16);
    k_fill2<<<RANGES * CHUNKS * 2, 1024, 0, stream>>>(senders, receivers, coff, col);
    // 2 nodes per wave -> 50000 waves -> 12500 blocks of 256
    k_agg_post<<<12500, B, 0, stream>>>(row_start, col, (const unsigned*)h16, W2, b2, z);
    k_agg2_sigmoid<<<(N_NODES + B - 1) / B, B, 0, stream>>>(row_start, col, z, out);
}